// Round 4
// baseline (164.017 us; speedup 1.0000x reference)
//
#include <hip/hip_runtime.h>
#include <hip/hip_bf16.h>

// out[e] = relu(concat(x[src],x[dst]) @ W1 + b1) @ W2 + b2
// Phase 1: uv[n][0:256] = x[n]@W1[:256,:], uv[n][256:512] = x[n]@W1[256:,:]  (bf16)
// Phase 2: per-edge sum_k relu(uv[src][k]+uv[dst][256+k]+b1[k])*W2[k] + b2.

typedef short short8 __attribute__((ext_vector_type(8)));
typedef float f32x4 __attribute__((ext_vector_type(4)));

#define DINC 256
#define NOUTC 512

__device__ inline unsigned short f2bf(float f) {
  union { float f; unsigned u; } c; c.f = f;
  unsigned u = c.u;
  return (unsigned short)((u + 0x7FFFu + ((u >> 16) & 1u)) >> 16);  // RNE
}
__device__ inline float bf2f(unsigned short h) {
  union { unsigned u; float f; } c; c.u = ((unsigned)h) << 16;
  return c.f;
}

// Plain layout: W1t[j][k] = bf16(W1'[k][j]); j<256 -> W1 rows 0..255 (u-half),
// j>=256 -> W1 rows 256..511 (v-half).
__global__ void w1t_kernel(const float* __restrict__ W1, unsigned short* __restrict__ W1t) {
  int t = blockIdx.x * 256 + threadIdx.x;           // 0..131071
  int j = t >> 8, k = t & 255;
  float v = W1[(size_t)(k + ((j >= 256) ? 256 : 0)) * DINC + (j & 255)];
  W1t[(size_t)j * DINC + k] = f2bf(v);
}

// 512 thr = 8 waves (2m x 4n), block tile 128x128, wave tile 64x32, BK=64.
// A: wave-dense fp32 loads -> reg -> cvt -> XOR-swizzled LDS (dbuf, 32 KB total).
// B: per-lane 16B register loads from L2-resident W1t, reg-double-buffered.
// MFMA operands swapped -> lane holds 4 consecutive uv cols -> 8B stores.
__global__ __launch_bounds__(512, 4) void uv_gemm(const float* __restrict__ x,
                                                  const unsigned short* __restrict__ W1t,
                                                  unsigned short* __restrict__ uv,
                                                  int Nn, int m_tiles) {
  __shared__ unsigned short As[2][128 * 64];   // 2 x 16 KB

  // XCD-bijective swizzle, bn-fastest (4 bn-tiles of one A-panel share an XCD L2)
  int nwg = gridDim.x;
  int q = nwg >> 3, r = nwg & 7;
  int xcd = blockIdx.x & 7, rank = blockIdx.x >> 3;
  int L = (xcd < r) ? (xcd * (q + 1) + rank) : (r * (q + 1) + (xcd - r) * q + rank);
  int bm = L >> 2, bn = L & 3;

  int tid = threadIdx.x, lane = tid & 63, w = tid >> 6;
  int wm = w >> 2, wn = w & 3;
  int lr = lane & 15, kg = lane >> 4;
  int m0 = bm * 128 + wm * 64;
  int n0 = bn * 128 + wn * 32;

  // A staging: thread t, pass j: flat float4 idx f = j*512 + t -> row = f>>4,
  // chunk c4 = f&15. Each instr = 64 consecutive float4 = 1 KB dense.
  int c4 = tid & 15, rb = tid >> 4;            // rows rb + j*32

  f32x4 acc[4][2] = {};
  float4 ar[4];
  short8 breg[2][4];                           // [buf][ks*2+nf]

#define ISSUE_A(KT)                                                            \
  {                                                                            \
    _Pragma("unroll")                                                          \
    for (int j = 0; j < 4; ++j) {                                              \
      int grow = bm * 128 + j * 32 + rb;                                       \
      if (grow >= Nn) grow = Nn - 1;                                           \
      ar[j] = *((const float4*)(x + (size_t)grow * DINC + (KT) * 64) + c4);    \
    }                                                                          \
  }

#define LOAD_B(KT, BUF)                                                        \
  {                                                                            \
    _Pragma("unroll")                                                          \
    for (int ks = 0; ks < 2; ++ks)                                             \
      _Pragma("unroll")                                                        \
      for (int nf = 0; nf < 2; ++nf)                                           \
        breg[BUF][ks * 2 + nf] = *(const short8*)(                             \
            W1t + (size_t)(n0 + nf * 16 + lr) * DINC +                         \
            (KT) * 64 + ks * 32 + kg * 8);                                     \
  }

#define WRITE_A(BUF)                                                           \
  {                                                                            \
    _Pragma("unroll")                                                          \
    for (int j = 0; j < 4; ++j) {                                              \
      int rl = j * 32 + rb;                                                    \
      ushort4 pk;                                                              \
      pk.x = f2bf(ar[j].x); pk.y = f2bf(ar[j].y);                              \
      pk.z = f2bf(ar[j].z); pk.w = f2bf(ar[j].w);                              \
      char* dp = (char*)&As[BUF][0] + rl * 128 +                               \
                 ((((c4 >> 1) ^ (rl & 7)) << 4) | ((c4 & 1) << 3));            \
      *(ushort4*)dp = pk;                                                      \
    }                                                                          \
  }

  ISSUE_A(0);
  LOAD_B(0, 0);
  WRITE_A(0);
  __syncthreads();

#pragma unroll
  for (int kt = 0; kt < 4; ++kt) {
    const int b = kt & 1;
    if (kt < 3) { ISSUE_A(kt + 1); LOAD_B(kt + 1, b ^ 1); }

#pragma unroll
    for (int ks = 0; ks < 2; ++ks) {
      short8 af[4];
#pragma unroll
      for (int mf = 0; mf < 4; ++mf) {
        int row = wm * 64 + mf * 16 + lr;
        int phys = (ks * 4 + kg) ^ (lr & 7);
        af[mf] = *(const short8*)((char*)&As[b][0] + row * 128 + phys * 16);
      }
#pragma unroll
      for (int mf = 0; mf < 4; ++mf)
#pragma unroll
        for (int nf = 0; nf < 2; ++nf)
          acc[mf][nf] = __builtin_amdgcn_mfma_f32_16x16x32_bf16(
              breg[b][ks * 2 + nf], af[mf], acc[mf][nf], 0, 0, 0);
    }

    if (kt < 3) { WRITE_A(b ^ 1); __syncthreads(); }
  }

  // Swapped-operand C/D layout: lane holds row m = m0+mf*16+lr,
  // cols n0+nf*16+kg*4 + (0..3) -> 8B row-contiguous stores.
#pragma unroll
  for (int mf = 0; mf < 4; ++mf) {
    int m = m0 + mf * 16 + lr;
    if (m < Nn) {
      unsigned short* orow = uv + (size_t)m * NOUTC;
#pragma unroll
      for (int nf = 0; nf < 2; ++nf) {
        ushort4 pk;
        pk.x = f2bf(acc[mf][nf][0]);
        pk.y = f2bf(acc[mf][nf][1]);
        pk.z = f2bf(acc[mf][nf][2]);
        pk.w = f2bf(acc[mf][nf][3]);
        *(ushort4*)(orow + n0 + nf * 16 + kg * 4) = pk;
      }
    }
  }
#undef ISSUE_A
#undef LOAD_B
#undef WRITE_A
}

// Quarter-wave (16 lanes) per edge: lane owns 16 of 256 channels.
__global__ __launch_bounds__(256) void edge_kernel(const int* __restrict__ eliW,
                                                   const unsigned short* __restrict__ uv,
                                                   const float* __restrict__ b1,
                                                   const float* __restrict__ W2,
                                                   const float* __restrict__ b2,
                                                   float* __restrict__ out, int E) {
  int tid = threadIdx.x;
  int ql = tid & 15;
  bool is64 = ((eliW[1] | eliW[3] | eliW[5] | eliW[7] | eliW[9] | eliW[11]) == 0);
  int shift = is64 ? 1 : 0;

  float bl[16], wl[16];
  *(float4*)(bl + 0)  = *(const float4*)(b1 + ql * 8);
  *(float4*)(bl + 4)  = *(const float4*)(b1 + ql * 8 + 4);
  *(float4*)(bl + 8)  = *(const float4*)(b1 + 128 + ql * 8);
  *(float4*)(bl + 12) = *(const float4*)(b1 + 128 + ql * 8 + 4);
  *(float4*)(wl + 0)  = *(const float4*)(W2 + ql * 8);
  *(float4*)(wl + 4)  = *(const float4*)(W2 + ql * 8 + 4);
  *(float4*)(wl + 8)  = *(const float4*)(W2 + 128 + ql * 8);
  *(float4*)(wl + 12) = *(const float4*)(W2 + 128 + ql * 8 + 4);
  float bias2 = b2[0];

  int qid = (blockIdx.x * blockDim.x + tid) >> 4;
  int nq = (gridDim.x * blockDim.x) >> 4;

  for (int e = qid; e < E; e += nq) {
    int src = eliW[((size_t)e) << shift];
    int dst = eliW[((size_t)(E + e)) << shift];
    const unsigned short* up = uv + (size_t)src * NOUTC;
    const unsigned short* vp = uv + (size_t)dst * NOUTC + DINC;
    short8 uu[2], vv[2];
    uu[0] = *(const short8*)(up + ql * 8);
    uu[1] = *(const short8*)(up + 128 + ql * 8);
    vv[0] = *(const short8*)(vp + ql * 8);
    vv[1] = *(const short8*)(vp + 128 + ql * 8);
    float s = 0.f;
#pragma unroll
    for (int g = 0; g < 2; ++g)
#pragma unroll
      for (int j = 0; j < 8; ++j) {
        float h = bf2f((unsigned short)uu[g][j]) + bf2f((unsigned short)vv[g][j]) + bl[g * 8 + j];
        s += fmaxf(h, 0.f) * wl[g * 8 + j];
      }
#pragma unroll
    for (int off = 8; off; off >>= 1) s += __shfl_xor(s, off, 64);
    if (ql == 0) out[e] = s + bias2;
  }
}

extern "C" void kernel_launch(void* const* d_in, const int* in_sizes, int n_in,
                              void* d_out, int out_size, void* d_ws, size_t ws_size,
                              hipStream_t stream) {
  const float* x   = (const float*)d_in[0];
  const int*   eli = (const int*)d_in[1];
  const float* W1  = (const float*)d_in[2];
  const float* b1  = (const float*)d_in[3];
  const float* W2  = (const float*)d_in[4];
  const float* b2  = (const float*)d_in[5];
  float* out = (float*)d_out;

  int Nn = in_sizes[0] / DINC;     // 100000
  int E  = in_sizes[1] / 2;        // 500000

  unsigned short* W1t = (unsigned short*)d_ws;              // 512*256*2 = 256 KB
  unsigned short* uv  = W1t + (size_t)NOUTC * DINC;         // Nn*512*2 ~ 102.4 MB

  w1t_kernel<<<512, 256, 0, stream>>>(W1, W1t);

  int m_tiles = (Nn + 127) / 128;                           // 782
  uv_gemm<<<m_tiles * (NOUTC / 128), 512, 0, stream>>>(x, W1t, uv, Nn, m_tiles);

  edge_kernel<<<2048, 256, 0, stream>>>(eli, uv, b1, W2, b2, out, E);
}